// Round 24
// baseline (24.515 us; speedup 1.0000x reference)
//
#include <hip/hip_runtime.h>
#include <cfloat>

// ChamferLossKL: bs=8, n=2048, d=4, fp32 in/out; one-pass pair matrix.
// s_ij = 2*KL(pred_i||gt_j) = dot(pa_i,ivb_j) + dot(mua_i,m2_j) + ca_i + cb_j
// loss[b] = 0.5*(sum_i min_j s + sum_j min_i s), both mins of the SAME s.
//
// R23 MEASUREMENT: gap ~0.7us, reduce ~1us -> main ~13us vs ~6us pipe
// model. Everything INSIDE the loop is falsified (FMA flavor, LDS atomics,
// bank conflicts, contention, spill). Untested: launch/drain shape --
// 1 block/CU x 1024thr means 256 heavyweight wgs ramp serially, each
// block's ~2us prologue (global latency + 36 expf + barrier) is fully
// exposed (no CU-mate to overlap), and the node drains on the slowest CU.
//
// R24: (16,8,4) = 512 blocks, CH_COLS=512, 2 blocks/CU. Same total work;
// prologue of one block hides under its CU-mate's sweep; ramp pipelines;
// LDS ~18KB/block. Sweep math unchanged (pk_fma, pure loop, jj=8
// unrolled). Two-dispatch + raw-bits global atomicMin (poison-proof,
// idempotent) locked from R18-R22.

#define TPB     1024
#define WAVES   16
#define RPT     8                 // rows per thread (4 packed pairs)
#define ROWSPB  (WAVES * RPT)     // 128 rows per block
#define NFIX    2048
#define CH_COLS 512               // columns per block (z-dim quarters)
#define NCH     (NFIX / CH_COLS)  // 4 column chunks
#define NRG     (NFIX / ROWSPB)   // 16 row groups
#define NJJ     (CH_COLS / 64)    // 8 column groups per block

typedef _Float16 half_t;
typedef __attribute__((ext_vector_type(2))) _Float16 half2_t;
typedef __attribute__((ext_vector_type(8))) _Float16 half8_t;

__device__ __forceinline__ half2_t pk_fma(half2_t a, half2_t b, half2_t c) {
#if __has_builtin(__builtin_elementwise_fma)
    return __builtin_elementwise_fma(a, b, c);     // v_pk_fma_f16
#else
    return a * b + c;
#endif
}
__device__ __forceinline__ half2_t pk_min(half2_t a, half2_t b) {
#if __has_builtin(__builtin_elementwise_min)
    return __builtin_elementwise_min(a, b);        // v_pk_min_f16
#else
    half2_t r;
    r[0] = a[0] < b[0] ? a[0] : b[0];
    r[1] = a[1] < b[1] ? a[1] : b[1];
    return r;
#endif
}

__global__ __launch_bounds__(TPB) void chamfer_kl_main(
    const float4* __restrict__ mu_a, const float4* __restrict__ lv_a,
    const float4* __restrict__ mu_b, const float4* __restrict__ lv_b,
    unsigned* __restrict__ colmin,   // [8][2048] float-bits, no init needed
    unsigned* __restrict__ rowmin)   // [8][2048] float-bits, no init needed
{
    __shared__ half8_t  sch[CH_COLS];        // ivb(4h), m2(4h)      8 KB
    __shared__ half2_t  scb2[CH_COLS];       // (cb, cb) fp16        2 KB
    __shared__ half2_t  scmw[WAVES * 256];   // per-wave col-mins    8 KB

    const int t    = threadIdx.x;
    const int rg   = blockIdx.x;     // 16 row groups
    const int b    = blockIdx.y;     // 8 batches
    const int ch   = blockIdx.z;     // 4 column chunks
    const int lane = t & 63;
    const int wid  = t >> 6;
    const int n    = NFIX;

    // ---- stage this chunk's column records (gts -> B-type), t<512
    if (t < CH_COLS) {
        const int j = ch * CH_COLS + t;
        float4 mu = mu_b[(size_t)b * n + j];
        float4 lv = lv_b[(size_t)b * n + j];
        float ivx = __expf(-lv.x), ivy = __expf(-lv.y);
        float ivz = __expf(-lv.z), ivw = __expf(-lv.w);
        half8_t h;
        h[0] = (half_t)ivx;                 h[1] = (half_t)ivy;
        h[2] = (half_t)ivz;                 h[3] = (half_t)ivw;
        h[4] = (half_t)(-2.f * mu.x * ivx); h[5] = (half_t)(-2.f * mu.y * ivy);
        h[6] = (half_t)(-2.f * mu.z * ivz); h[7] = (half_t)(-2.f * mu.w * ivw);
        sch[t] = h;
        float cb = mu.x * mu.x * ivx + mu.y * mu.y * ivy
                 + mu.z * mu.z * ivz + mu.w * mu.w * ivw
                 + lv.x + lv.y + lv.z + lv.w;
        half2_t cb2; cb2[0] = (half_t)cb; cb2[1] = (half_t)cb;
        scb2[t] = cb2;
    }

    // ---- row records (preds -> A-type), 8 rows = 4 packed pairs
    const int rbase = rg * ROWSPB + wid * RPT;
    half2_t rowpk[4][8];
    half2_t ca2[4], rmin2[4];
    const half_t hinf = (half_t)__builtin_huge_valf();
#pragma unroll
    for (int p = 0; p < 4; ++p) {
        float4 muA = mu_a[(size_t)b * n + rbase + 2 * p];
        float4 lvA = lv_a[(size_t)b * n + rbase + 2 * p];
        float4 muB = mu_a[(size_t)b * n + rbase + 2 * p + 1];
        float4 lvB = lv_a[(size_t)b * n + rbase + 2 * p + 1];
        rowpk[p][0][0] = (half_t)(__expf(lvA.x) + muA.x * muA.x);
        rowpk[p][0][1] = (half_t)(__expf(lvB.x) + muB.x * muB.x);
        rowpk[p][1][0] = (half_t)(__expf(lvA.y) + muA.y * muA.y);
        rowpk[p][1][1] = (half_t)(__expf(lvB.y) + muB.y * muB.y);
        rowpk[p][2][0] = (half_t)(__expf(lvA.z) + muA.z * muA.z);
        rowpk[p][2][1] = (half_t)(__expf(lvB.z) + muB.z * muB.z);
        rowpk[p][3][0] = (half_t)(__expf(lvA.w) + muA.w * muA.w);
        rowpk[p][3][1] = (half_t)(__expf(lvB.w) + muB.w * muB.w);
        rowpk[p][4][0] = (half_t)muA.x;  rowpk[p][4][1] = (half_t)muB.x;
        rowpk[p][5][0] = (half_t)muA.y;  rowpk[p][5][1] = (half_t)muB.y;
        rowpk[p][6][0] = (half_t)muA.z;  rowpk[p][6][1] = (half_t)muB.z;
        rowpk[p][7][0] = (half_t)muA.w;  rowpk[p][7][1] = (half_t)muB.w;
        ca2[p][0] = (half_t)(-(lvA.x + lvA.y + lvA.z + lvA.w) - 4.f);
        ca2[p][1] = (half_t)(-(lvB.x + lvB.y + lvB.z + lvB.w) - 4.f);
        rmin2[p][0] = hinf; rmin2[p][1] = hinf;
    }
    __syncthreads();

    // ---- main sweep: 128 rows x 512 cols, PURE loop (no atomics)
    half2_t cm2[NJJ / 2];
#pragma unroll
    for (int jj = 0; jj < NJJ; ++jj) {              // 8 iterations
        const int j = (jj << 6) + lane;
        const half8_t hc  = sch[j];                 // ds_read_b128 (imm off)
        const half2_t cb2 = scb2[j];                // ds_read_b32  (imm off)
        half2_t cmin2; cmin2[0] = hinf; cmin2[1] = hinf;
#pragma unroll
        for (int p = 0; p < 4; ++p) {               // 4 row-pairs
            half2_t acc = ca2[p];                   // seeded with (caA, caB)
#pragma unroll
            for (int k = 0; k < 8; ++k) {           // 8 comps, both rows/op
                half2_t cs; cs[0] = hc[k]; cs[1] = hc[k];
                acc = pk_fma(rowpk[p][k], cs, acc);
            }
            half2_t s2 = acc + cb2;                 // s = 2*KL (fp16 pair)
            rmin2[p] = pk_min(rmin2[p], s2);
            cmin2    = pk_min(cmin2, s2);
        }
        half_t m = cmin2[0] < cmin2[1] ? cmin2[0] : cmin2[1];
        cm2[jj >> 1][jj & 1] = m;                   // compile-time indices
    }

    // ---- per-wave col-min publish to LDS (conflict-free b32 writes)
#pragma unroll
    for (int g2 = 0; g2 < NJJ / 2; ++g2)
        scmw[wid * 256 + g2 * 64 + lane] = cm2[g2];
    __syncthreads();

    // ---- cross-wave fold: thread t (<512) owns column t
    if (t < CH_COLS) {
        const int g      = t >> 6;          // column group = jj (0..7)
        const int parity = g & 1;
        const int idx    = (g >> 1) * 64 + lane;
        half2_t h2 = scmw[idx];
#pragma unroll
        for (int w = 1; w < WAVES; ++w)
            h2 = pk_min(h2, scmw[w * 256 + idx]);
        float m = parity ? (float)h2[1] : (float)h2[0];
        // KL>=0: clamp -> f32 bits monotone as uint; poison always loses
        atomicMin(&colmin[(size_t)b * n + ch * CH_COLS + t],
                  __float_as_uint(fmaxf(m, 0.f)));
    }

    // ---- row-min epilogue: min across 64 lanes per row, then global
#pragma unroll
    for (int p = 0; p < 4; ++p) {
        float m0 = (float)rmin2[p][0];
        float m1 = (float)rmin2[p][1];
#pragma unroll
        for (int off = 32; off; off >>= 1) {
            m0 = fminf(m0, __shfl_xor(m0, off, 64));
            m1 = fminf(m1, __shfl_xor(m1, off, 64));
        }
        if (lane == 0) {
            atomicMin(&rowmin[(size_t)b * n + rbase + 2 * p],
                      __float_as_uint(fmaxf(m0, 0.f)));
            atomicMin(&rowmin[(size_t)b * n + rbase + 2 * p + 1],
                      __float_as_uint(fmaxf(m1, 0.f)));
        }
    }
}

// One block per batch (256 threads): uint4 loads over 2x2048 mins, sum.
__global__ __launch_bounds__(256) void chamfer_kl_reduce(
    const uint4* __restrict__ colmin4,   // [8][512]
    const uint4* __restrict__ rowmin4,   // [8][512]
    float* __restrict__ out)
{
    __shared__ float fsum[4];
    const int t    = threadIdx.x;
    const int b    = blockIdx.x;
    const int lane = t & 63;
    const int wid  = t >> 6;

    float acc = 0.f;
#pragma unroll
    for (int it = 0; it < 2; ++it) {        // 512 uint4 per array per batch
        const int j = it * 256 + t;
        uint4 c = colmin4[(size_t)b * 512 + j];
        uint4 r = rowmin4[(size_t)b * 512 + j];
        acc += __uint_as_float(c.x) + __uint_as_float(c.y)
             + __uint_as_float(c.z) + __uint_as_float(c.w);
        acc += __uint_as_float(r.x) + __uint_as_float(r.y)
             + __uint_as_float(r.z) + __uint_as_float(r.w);
    }
#pragma unroll
    for (int off = 32; off; off >>= 1) acc += __shfl_xor(acc, off, 64);
    if (lane == 0) fsum[wid] = acc;
    __syncthreads();
    if (t == 0)
        out[b] = 0.5f * (fsum[0] + fsum[1] + fsum[2] + fsum[3]);
}

extern "C" void kernel_launch(void* const* d_in, const int* in_sizes, int n_in,
                              void* d_out, int out_size, void* d_ws, size_t ws_size,
                              hipStream_t stream) {
    const float4* mu_a = (const float4*)d_in[0];  // mu_preds
    const float4* lv_a = (const float4*)d_in[1];  // logvar_preds
    const float4* mu_b = (const float4*)d_in[2];  // mu_gts
    const float4* lv_b = (const float4*)d_in[3];  // logvar_gts

    const int bs = out_size;  // 8

    unsigned* colmin = (unsigned*)d_ws;               // 8*2048 uints (64 KB)
    unsigned* rowmin = colmin + (size_t)bs * NFIX;    // 8*2048 uints (64 KB)

    dim3 grid(NRG, bs, NCH);  // (16, 8, 4) = 512 blocks = 2/CU
    chamfer_kl_main<<<grid, TPB, 0, stream>>>(mu_a, lv_a, mu_b, lv_b,
                                              colmin, rowmin);
    chamfer_kl_reduce<<<bs, 256, 0, stream>>>((const uint4*)colmin,
                                              (const uint4*)rowmin,
                                              (float*)d_out);
}

// Round 25
// 19.742 us; speedup vs baseline: 1.2418x; 1.2418x over previous
//
#include <hip/hip_runtime.h>
#include <cfloat>

// ChamferLossKL: bs=8, n=2048, d=4, fp32 in/out; one-pass pair matrix.
// s_ij = 2*KL(pred_i||gt_j) = dot(pa_i,ivb_j) + dot(mua_i,m2_j) + ca_i + cb_j
//   row (pred) record: pa = exp(lva)+mua^2, mua, ca = -sum(lva)-4
//   col (gt)   record: ivb = exp(-lvb), m2 = -2*mub*ivb, cb
// loss[b] = 0.5*(sum_i min_j s + sum_j min_i s), both mins of the SAME s.
//
// TERMINAL KERNEL: exact restore of R21 (19.69us, session best).
// Hypothesis ledger for main-kernel time (~13us vs ~5us pipe model):
//   spill            - falsified (live-set fits, no scratch traffic)
//   FMA flavor       - falsified (fdot2 -> pk_fma: -1us only)
//   LDS atomics      - falsified (R22 zero-atomic sweep: no change)
//   bank conflicts   - falsified (counter = 0)
//   atomic contention- falsified (stagger: no change)
//   node/graph gap   - measured 0.7us (R20/R23 duplicate-node probes)
//   launch shape     - falsified (R24 2 blocks/CU: +4.7us REGRESSION)
// Remaining explanation is environmental (effective clock during replay),
// invariant to code structure. 19.7us = practical optimum in this harness.
//
// Structure: two plain dispatches (in-kernel cross-block finalize = dead
// end, R4/5/8/9/16/17: 59-118us cross-XCD coherence tax); global atomicMin
// on raw float bits (KL>=0 clamped -> monotone as uint; 0xAA poison always
// loses -> no init kernel; replays idempotent).

#define TPB     1024
#define WAVES   16
#define RPT     8                 // rows per thread (4 packed pairs)
#define ROWSPB  (WAVES * RPT)     // 128 rows per block
#define NFIX    2048
#define CH_COLS 1024              // columns per block (z-dim halves)
#define NRG     (NFIX / ROWSPB)   // 16 row groups

typedef _Float16 half_t;
typedef __attribute__((ext_vector_type(2))) _Float16 half2_t;
typedef __attribute__((ext_vector_type(8))) _Float16 half8_t;

__device__ __forceinline__ half2_t pk_fma(half2_t a, half2_t b, half2_t c) {
#if __has_builtin(__builtin_elementwise_fma)
    return __builtin_elementwise_fma(a, b, c);     // v_pk_fma_f16
#else
    return a * b + c;
#endif
}
__device__ __forceinline__ half2_t pk_min(half2_t a, half2_t b) {
#if __has_builtin(__builtin_elementwise_min)
    return __builtin_elementwise_min(a, b);        // v_pk_min_f16
#else
    half2_t r;
    r[0] = a[0] < b[0] ? a[0] : b[0];
    r[1] = a[1] < b[1] ? a[1] : b[1];
    return r;
#endif
}

__global__ __launch_bounds__(TPB) void chamfer_kl_main(
    const float4* __restrict__ mu_a, const float4* __restrict__ lv_a,
    const float4* __restrict__ mu_b, const float4* __restrict__ lv_b,
    unsigned* __restrict__ colmin,   // [8][2048] float-bits, no init needed
    unsigned* __restrict__ rowmin)   // [8][2048] float-bits, no init needed
{
    __shared__ half8_t  sch[CH_COLS];   // ivb(4h), m2(4h)   16 KB
    __shared__ half2_t  scb2[CH_COLS];  // (cb, cb) fp16      4 KB
    __shared__ unsigned scm[CH_COLS];   // col-min f32 bits   4 KB

    const int t    = threadIdx.x;
    const int rg   = blockIdx.x;     // 16 row groups
    const int b    = blockIdx.y;     // 8 batches
    const int ch   = blockIdx.z;     // 2 column halves
    const int lane = t & 63;
    const int wid  = t >> 6;
    const int n    = NFIX;

    // ---- stage this half's column records (gts -> B-type), 1 per thread
    {
        const int j = ch * CH_COLS + t;
        float4 mu = mu_b[(size_t)b * n + j];
        float4 lv = lv_b[(size_t)b * n + j];
        float ivx = __expf(-lv.x), ivy = __expf(-lv.y);
        float ivz = __expf(-lv.z), ivw = __expf(-lv.w);
        half8_t h;
        h[0] = (half_t)ivx;                 h[1] = (half_t)ivy;
        h[2] = (half_t)ivz;                 h[3] = (half_t)ivw;
        h[4] = (half_t)(-2.f * mu.x * ivx); h[5] = (half_t)(-2.f * mu.y * ivy);
        h[6] = (half_t)(-2.f * mu.z * ivz); h[7] = (half_t)(-2.f * mu.w * ivw);
        sch[j - ch * CH_COLS] = h;
        float cb = mu.x * mu.x * ivx + mu.y * mu.y * ivy
                 + mu.z * mu.z * ivz + mu.w * mu.w * ivw
                 + lv.x + lv.y + lv.z + lv.w;
        half2_t cb2; cb2[0] = (half_t)cb; cb2[1] = (half_t)cb;
        scb2[t] = cb2;
        scm[t]  = 0x7F7FFFFFu;           // FLT_MAX bits
    }

    // ---- row records (preds -> A-type), 8 rows = 4 packed pairs
    // rowpk[p][k] = half2(component k of row 2p, component k of row 2p+1)
    // k=0..3: pa components; k=4..7: mua components.
    const int rbase = rg * ROWSPB + wid * RPT;
    half2_t rowpk[4][8];
    half2_t ca2[4], rmin2[4];
    const half_t hinf = (half_t)__builtin_huge_valf();
#pragma unroll
    for (int p = 0; p < 4; ++p) {
        float4 muA = mu_a[(size_t)b * n + rbase + 2 * p];
        float4 lvA = lv_a[(size_t)b * n + rbase + 2 * p];
        float4 muB = mu_a[(size_t)b * n + rbase + 2 * p + 1];
        float4 lvB = lv_a[(size_t)b * n + rbase + 2 * p + 1];
        rowpk[p][0][0] = (half_t)(__expf(lvA.x) + muA.x * muA.x);
        rowpk[p][0][1] = (half_t)(__expf(lvB.x) + muB.x * muB.x);
        rowpk[p][1][0] = (half_t)(__expf(lvA.y) + muA.y * muA.y);
        rowpk[p][1][1] = (half_t)(__expf(lvB.y) + muB.y * muB.y);
        rowpk[p][2][0] = (half_t)(__expf(lvA.z) + muA.z * muA.z);
        rowpk[p][2][1] = (half_t)(__expf(lvB.z) + muB.z * muB.z);
        rowpk[p][3][0] = (half_t)(__expf(lvA.w) + muA.w * muA.w);
        rowpk[p][3][1] = (half_t)(__expf(lvB.w) + muB.w * muB.w);
        rowpk[p][4][0] = (half_t)muA.x;  rowpk[p][4][1] = (half_t)muB.x;
        rowpk[p][5][0] = (half_t)muA.y;  rowpk[p][5][1] = (half_t)muB.y;
        rowpk[p][6][0] = (half_t)muA.z;  rowpk[p][6][1] = (half_t)muB.z;
        rowpk[p][7][0] = (half_t)muA.w;  rowpk[p][7][1] = (half_t)muB.w;
        ca2[p][0] = (half_t)(-(lvA.x + lvA.y + lvA.z + lvA.w) - 4.f);
        ca2[p][1] = (half_t)(-(lvB.x + lvB.y + lvB.z + lvB.w) - 4.f);
        rmin2[p][0] = hinf; rmin2[p][1] = hinf;
    }
    __syncthreads();

    // ---- main sweep: 128 rows x 1024 cols, each pair once, s = 2*KL.
    // Wave-staggered column groups: no same-address scm contention.
    for (int jj = 0; jj < CH_COLS / 64; ++jj) {     // 16 iterations
        const int grp = (jj + wid) & (CH_COLS / 64 - 1);
        const int j = (grp << 6) + lane;
        const half8_t hc  = sch[j];                 // one ds_read_b128
        const half2_t cb2 = scb2[j];                // one ds_read_b32
        half2_t cmin2; cmin2[0] = hinf; cmin2[1] = hinf;
#pragma unroll
        for (int p = 0; p < 4; ++p) {               // 4 row-pairs
            half2_t acc = ca2[p];                   // seeded with (caA, caB)
#pragma unroll
            for (int k = 0; k < 8; ++k) {           // 8 comps, both rows/op
                half2_t cs; cs[0] = hc[k]; cs[1] = hc[k];  // opsel-foldable
                acc = pk_fma(rowpk[p][k], cs, acc);
            }
            half2_t s2 = acc + cb2;                 // s = 2*KL (fp16 pair)
            rmin2[p] = pk_min(rmin2[p], s2);
            cmin2    = pk_min(cmin2, s2);
        }
        float cm = fminf((float)cmin2[0], (float)cmin2[1]);
        // KL>=0: clamp -> f32 bits monotone as uint
        atomicMin(&scm[j], __float_as_uint(fmaxf(cm, 0.f)));
    }
    __syncthreads();

    // ---- publish: global atomicMin on raw bits (poison always loses)
    atomicMin(&colmin[(size_t)b * n + ch * CH_COLS + t], scm[t]);

#pragma unroll
    for (int p = 0; p < 4; ++p) {
        float m0 = (float)rmin2[p][0];
        float m1 = (float)rmin2[p][1];
#pragma unroll
        for (int off = 32; off; off >>= 1) {
            m0 = fminf(m0, __shfl_xor(m0, off, 64));
            m1 = fminf(m1, __shfl_xor(m1, off, 64));
        }
        if (lane == 0) {
            atomicMin(&rowmin[(size_t)b * n + rbase + 2 * p],
                      __float_as_uint(fmaxf(m0, 0.f)));
            atomicMin(&rowmin[(size_t)b * n + rbase + 2 * p + 1],
                      __float_as_uint(fmaxf(m1, 0.f)));
        }
    }
}

// One block per batch (256 threads): uint4 loads over 2x2048 mins, sum.
__global__ __launch_bounds__(256) void chamfer_kl_reduce(
    const uint4* __restrict__ colmin4,   // [8][512]
    const uint4* __restrict__ rowmin4,   // [8][512]
    float* __restrict__ out)
{
    __shared__ float fsum[4];
    const int t    = threadIdx.x;
    const int b    = blockIdx.x;
    const int lane = t & 63;
    const int wid  = t >> 6;

    float acc = 0.f;
#pragma unroll
    for (int it = 0; it < 2; ++it) {        // 512 uint4 per array per batch
        const int j = it * 256 + t;
        uint4 c = colmin4[(size_t)b * 512 + j];
        uint4 r = rowmin4[(size_t)b * 512 + j];
        acc += __uint_as_float(c.x) + __uint_as_float(c.y)
             + __uint_as_float(c.z) + __uint_as_float(c.w);
        acc += __uint_as_float(r.x) + __uint_as_float(r.y)
             + __uint_as_float(r.z) + __uint_as_float(r.w);
    }
#pragma unroll
    for (int off = 32; off; off >>= 1) acc += __shfl_xor(acc, off, 64);
    if (lane == 0) fsum[wid] = acc;
    __syncthreads();
    if (t == 0)
        out[b] = 0.5f * (fsum[0] + fsum[1] + fsum[2] + fsum[3]);
}

extern "C" void kernel_launch(void* const* d_in, const int* in_sizes, int n_in,
                              void* d_out, int out_size, void* d_ws, size_t ws_size,
                              hipStream_t stream) {
    const float4* mu_a = (const float4*)d_in[0];  // mu_preds
    const float4* lv_a = (const float4*)d_in[1];  // logvar_preds
    const float4* mu_b = (const float4*)d_in[2];  // mu_gts
    const float4* lv_b = (const float4*)d_in[3];  // logvar_gts

    const int bs = out_size;  // 8

    unsigned* colmin = (unsigned*)d_ws;               // 8*2048 uints (64 KB)
    unsigned* rowmin = colmin + (size_t)bs * NFIX;    // 8*2048 uints (64 KB)

    dim3 grid(NRG, bs, 2);  // (16, 8, 2) = 256 blocks = 1/CU
    chamfer_kl_main<<<grid, TPB, 0, stream>>>(mu_a, lv_a, mu_b, lv_b,
                                              colmin, rowmin);
    chamfer_kl_reduce<<<bs, 256, 0, stream>>>((const uint4*)colmin,
                                              (const uint4*)rowmin,
                                              (float*)d_out);
}